// Round 4
// baseline (137.332 us; speedup 1.0000x reference)
//
#include <hip/hip_runtime.h>

typedef float f32x2 __attribute__((ext_vector_type(2)));

#define NPTS  16384
#define BATCH 16

// LDS float offsets
#define OFF_W1   0       // W1 [16][20] f32
#define OFF_B1   320     // b1 [16] f32
#define OFF_VB   336     // v [16][16] f32
#define OFF_TB   592     // t [16][16] f32 (8B-aligned: 2368B)
#define OFF_HBD  848     // h [16][16] DOUBLE (512 floats; 3392B, 8-aligned)
#define OFF_U    1360    // phase A: x[16][16]; chunks: P0+P1; epilogue: g doubles [16][16*17]
#define P_STRIDE 4352
#define LDS_FLOATS (OFF_U + 2 * P_STRIDE)   // 10064 floats = 40256 B -> 4 blocks/CU

__device__ __forceinline__ void pkfma(f32x2& d, f32x2 a, f32x2 b) {
    asm("v_pk_fma_f32 %0, %1, %2, %0" : "+v"(d) : "v"(a), "v"(b));
}
__device__ __forceinline__ f32x2 pkmul(f32x2 a, f32x2 b) {
    f32x2 d;
    asm("v_pk_mul_f32 %0, %1, %2" : "=v"(d) : "v"(a), "v"(b));
    return d;
}
__device__ __forceinline__ double shfl_d(double x, int src) {
    long long v = __double_as_longlong(x);
    int lo = __shfl((int)(v & 0xffffffffLL), src, 16);
    int hi = __shfl((int)(v >> 32), src, 16);
    return __longlong_as_double(((long long)hi << 32) | (unsigned int)lo);
}
__device__ __forceinline__ double shfl_xor_d(double x, int m) {
    long long v = __double_as_longlong(x);
    int lo = __shfl_xor((int)(v & 0xffffffffLL), m, 16);
    int hi = __shfl_xor((int)(v >> 32), m, 16);
    return __longlong_as_double(((long long)hi << 32) | (unsigned int)lo);
}

__launch_bounds__(256, 4)
__global__ void conn_kernel(const float* __restrict__ inp,
                            const float* __restrict__ W1g,
                            const float* __restrict__ b1g,
                            const float* __restrict__ W2g,
                            const float* __restrict__ b2g,
                            float* __restrict__ out)
{
    __shared__ float SH[LDS_FLOATS];
    const int tid  = threadIdx.x;
    const int i_of = tid >> 4;
    const int j_of = tid & 15;

    // ---- per-thread: f32 S2 row (packed) for the J loop ----
    const int pT = (j_of << 4) | i_of;
    f32x2 s2[8];
    {
        const float4* wa = reinterpret_cast<const float4*>(W2g + tid * 16);
        const float4* wb = reinterpret_cast<const float4*>(W2g + pT  * 16);
        #pragma unroll
        for (int q = 0; q < 4; ++q) {
            float4 A = wa[q], B = wb[q];
            s2[2*q+0] = f32x2{A.x + B.x, A.y + B.y};
            s2[2*q+1] = f32x2{A.z + B.z, A.w + B.w};
        }
    }

    // ---- stage W1 [k][20], b1, inputs (x overlaid into U region) ----
    SH[OFF_W1 + i_of * 20 + j_of] = W1g[tid];
    if (tid < 16) SH[OFF_B1 + tid] = b1g[tid];

    const int base = blockIdx.x * BATCH;
    if (tid < 128) {
        float4 vle = reinterpret_cast<const float4*>(inp + base * 32)[tid];
        int idx = tid * 4, pt = idx >> 5, c = idx & 31;
        float* dst = (c < 16) ? &SH[OFF_U  + pt * 16 + c]
                              : &SH[OFF_VB + pt * 16 + (c - 16)];
        dst[0] = vle.x; dst[1] = vle.y; dst[2] = vle.z; dst[3] = vle.w;
    }
    __syncthreads();

    // ---- phase A (f64): pre, h=tanh, t=1-h^2  (thread = (pt=i_of, k=j_of)) ----
    {
        const int pt = i_of, k = j_of;
        const float* wrow = &SH[OFF_W1 + k * 20];
        const float* xrow = &SH[OFF_U  + pt * 16];
        double pre = (double)SH[OFF_B1 + k];
        #pragma unroll
        for (int l = 0; l < 16; ++l)
            pre = fma((double)wrow[l], (double)xrow[l], pre);
        double h = tanh(pre);
        reinterpret_cast<double*>(&SH[OFF_HBD])[pt * 16 + k] = h;
        SH[OFF_TB + pt * 16 + k] = (float)(1.0 - h * h);
    }
    __syncthreads();

    float* const P0 = &SH[OFF_U];
    float* const P1 = &SH[OFF_U + P_STRIDE];

    // ---- main loop: 8 chunks of 2 points ----
    #pragma unroll 1
    for (int ch = 0; ch < 8; ++ch) {
        const int ptA = 2 * ch, ptB = 2 * ch + 1;

        f32x2 cA[8], cB[8], jA[8], jB[8];
        {
            const f32x2* tA2 = reinterpret_cast<const f32x2*>(&SH[OFF_TB + ptA * 16]);
            const f32x2* tB2 = reinterpret_cast<const f32x2*>(&SH[OFF_TB + ptB * 16]);
            #pragma unroll
            for (int m = 0; m < 8; ++m) {
                cA[m] = pkmul(s2[m], tA2[m]);
                cB[m] = pkmul(s2[m], tB2[m]);
                jA[m] = f32x2{0.f, 0.f};
                jB[m] = f32x2{0.f, 0.f};
            }
        }

        // J[p][l] = sum_k c[k] * W1[k][l]  (packed f32, bitwise == scalar fma chain)
        #pragma unroll
        for (int k = 0; k < 16; ++k) {
            const float4* w4 = reinterpret_cast<const float4*>(&SH[OFF_W1 + k * 20]);
            float4 w0 = w4[0], w1 = w4[1], w2 = w4[2], w3 = w4[3];
            f32x2 wp[8] = { {w0.x,w0.y},{w0.z,w0.w},{w1.x,w1.y},{w1.z,w1.w},
                            {w2.x,w2.y},{w2.z,w2.w},{w3.x,w3.y},{w3.z,w3.w} };
            float ca = cA[k >> 1][k & 1], cb = cB[k >> 1][k & 1];
            f32x2 ca2 = {ca, ca}, cb2 = {cb, cb};
            #pragma unroll
            for (int m = 0; m < 8; ++m) pkfma(jA[m], wp[m], ca2);
            #pragma unroll
            for (int m = 0; m < 8; ++m) pkfma(jB[m], wp[m], cb2);
        }

        // P[i,j,l] = v_i v_j J[i,j,l]^2  at l*272 + j*17 + i (2-way max on read/write)
        {
            float pfA = SH[OFF_VB + ptA * 16 + i_of] * SH[OFF_VB + ptA * 16 + j_of];
            float pfB = SH[OFF_VB + ptB * 16 + i_of] * SH[OFF_VB + ptB * 16 + j_of];
            #pragma unroll
            for (int l = 0; l < 16; ++l) {
                float a = jA[l >> 1][l & 1], b = jB[l >> 1][l & 1];
                P0[l * 272 + j_of * 17 + i_of] = pfA * a * a;
                P1[l * 272 + j_of * 17 + i_of] = pfB * b * b;
            }
        }
        __syncthreads();

        // phase C (f64 accumulate): A[a] = sum_{b,j} J[a,b,j] * P[b,j,a]
        {
            double sA = 0.0, sB = 0.0;
            #pragma unroll
            for (int j = 0; j < 16; ++j) {
                sA = fma((double)jA[j >> 1][j & 1],
                         (double)P0[i_of * 272 + j * 17 + j_of], sA);
                sB = fma((double)jB[j >> 1][j & 1],
                         (double)P1[i_of * 272 + j * 17 + j_of], sB);
            }
            #pragma unroll
            for (int m = 1; m < 16; m <<= 1) {
                sA += shfl_xor_d(sA, m);
                sB += shfl_xor_d(sB, m);
            }
            // park A in P's padding holes (offset ...+16 never read/written as P)
            if (j_of == 0) {
                P0[i_of * 272 + ch * 17 + 16] = (float)sA;   // A_{ptA}[i_of]
                P1[i_of * 272 + ch * 17 + 16] = (float)sB;   // A_{ptB}[i_of]
            }
        }
        __syncthreads();
    }

    // ---- pull rhs (A) out of the holes before g overwrites the U region ----
    float rhsf;
    {
        const int pt = i_of, r = j_of;
        const float* Pb = (pt & 1) ? P1 : P0;
        rhsf = Pb[r * 272 + (pt >> 1) * 17 + 16];
    }
    __syncthreads();

    // ---- g formation (f64): g[i,j]_pt = b2s + sum_k s2d[k] h_pt[k] ----
    {
        double s2d[16];
        const float4* wa = reinterpret_cast<const float4*>(W2g + tid * 16);
        const float4* wb = reinterpret_cast<const float4*>(W2g + pT  * 16);
        #pragma unroll
        for (int q = 0; q < 4; ++q) {
            float4 A = wa[q], B = wb[q];
            s2d[4*q+0] = (double)A.x + (double)B.x;
            s2d[4*q+1] = (double)A.y + (double)B.y;
            s2d[4*q+2] = (double)A.z + (double)B.z;
            s2d[4*q+3] = (double)A.w + (double)B.w;
        }
        double bd = (double)b2g[tid] + (double)b2g[pT];

        double* GD = reinterpret_cast<double*>(&SH[OFF_U]);
        const double* HD = reinterpret_cast<const double*>(&SH[OFF_HBD]);
        #pragma unroll
        for (int pt = 0; pt < 16; ++pt) {
            const double* hrow = &HD[pt * 16];
            double acc = bd;
            #pragma unroll
            for (int k = 0; k < 16; ++k) acc = fma(s2d[k], hrow[k], acc);
            GD[pt * 272 + i_of * 17 + j_of] = acc;
        }
    }
    __syncthreads();

    // ---- phase D (f64): solve g y = A, dv = 0.5 y  (thread = (pt=i_of, r=j_of)) ----
    {
        const int pt = i_of, r = j_of;
        const double* GD = reinterpret_cast<const double*>(&SH[OFF_U]);
        double grow[16];
        const double* gr = &GD[pt * 272 + r * 17];
        #pragma unroll
        for (int c = 0; c < 16; ++c) grow[c] = gr[c];
        double rhs = (double)rhsf;

        bool done = false; int myvar = 0;
        #pragma unroll
        for (int s = 0; s < 16; ++s) {
            float bv = done ? -1.0f : (float)fabs(grow[s]);
            int bi = r;
            #pragma unroll
            for (int m = 8; m >= 1; m >>= 1) {
                float ov = __shfl_xor(bv, m, 16);
                int   oi = __shfl_xor(bi, m, 16);
                if (ov > bv || (ov == bv && oi < bi)) { bv = ov; bi = oi; }
            }
            double pv   = shfl_d(grow[s], bi);
            double prhs = shfl_d(rhs,     bi);
            double invp = 1.0 / pv;
            bool   isP  = (r == bi);
            double f    = grow[s] * invp;
            #pragma unroll
            for (int c = s + 1; c < 16; ++c) {
                double pc  = shfl_d(grow[c], bi);
                double upd = fma(-f, pc, grow[c]);
                double piv = grow[c] * invp;
                grow[c] = isP ? piv : upd;
            }
            double updr = fma(-f, prhs, rhs);
            double pivr = rhs * invp;
            rhs = isP ? pivr : updr;
            if (isP) { done = true; myvar = s; }
        }

        const int n = base + pt;
        out[n * 32 + r]          = SH[OFF_VB + pt * 16 + r];
        out[n * 32 + 16 + myvar] = (float)(0.5 * rhs);
    }
}

extern "C" void kernel_launch(void* const* d_in, const int* in_sizes, int n_in,
                              void* d_out, int out_size, void* d_ws, size_t ws_size,
                              hipStream_t stream) {
    const float* inp = (const float*)d_in[1];
    const float* W1  = (const float*)d_in[2];
    const float* b1  = (const float*)d_in[3];
    const float* W2  = (const float*)d_in[4];
    const float* b2  = (const float*)d_in[5];
    float* outp = (float*)d_out;
    conn_kernel<<<dim3(NPTS / BATCH), 256, 0, stream>>>(inp, W1, b1, W2, b2, outp);
}